// Round 1
// baseline (11662.514 us; speedup 1.0000x reference)
//
#include <hip/hip_runtime.h>
#include <stdint.h>

// SpatialGRU on MI355X, round 3: single persistent kernel.
// Block = (column rc, batch-half bh); loops l=0..79. Cross-block handoff of
// h_left only, via 3-slot/column ring + progress flags using agent-scope
// relaxed atomics (sc0/sc1 -> LLC-coherent, no L2 invalidates so the weight
// stream stays L2-resident). h_top / h_diag live in LDS (fp32, padded to 132
// floats/row for bank spread). GEMM1 is K-split: kb {0..3,8..12} (ht/hd/x)
// run before the neighbor spin; only kb 4..7 (hl columns) wait on the flag.
// 160 blocks x 1024 thr, 152 KB LDS -> 1 block/CU, all co-resident (160<256).

typedef __bf16 bf16x8 __attribute__((ext_vector_type(8)));
typedef float  f32x4  __attribute__((ext_vector_type(4)));
typedef unsigned short ushort4v __attribute__((ext_vector_type(4)));
typedef unsigned short ushort2v __attribute__((ext_vector_type(2)));

#define QPITCH 424   // 416 q cols + 8 pad (bf16 elems)
#define HPITCH 132   // fp32 h rows padded +4 (bank spread: stride 132 -> step 4 banks)

__device__ int g_progress[160];   // cells completed per block (flag protocol)

__device__ __forceinline__ unsigned short f2bf(float x) {
  unsigned int u = __builtin_bit_cast(unsigned int, x);
  u = u + 0x7FFFu + ((u >> 16) & 1u);          // round-to-nearest-even
  return (unsigned short)(u >> 16);
}
__device__ __forceinline__ float bf2f(unsigned short h) {
  unsigned int u = ((unsigned int)h) << 16;
  return __builtin_bit_cast(float, u);
}
__device__ __forceinline__ float sigm(float x) {
  x = fminf(fmaxf(x, -30.f), 30.f);
  return 1.f / (1.f + __expf(-x));
}
__device__ __forceinline__ float tanh_fast(float x) {
  x = fminf(fmaxf(x, -15.f), 15.f);
  float e = __expf(2.f * x);
  return (e - 1.f) / (e + 1.f);
}

// ---------------------------------------------------------------------------
// prep: pack fused W' (1024 x 416) and WU' (128 x 384) into MFMA A-fragment
// order (unchanged from round 2) + zero the progress flags (agent-scope so
// the persistent kernel's sc1 reads see them through the LLC).
// ---------------------------------------------------------------------------
__global__ void prep_kernel(const float* __restrict__ Wr, const float* __restrict__ Wz,
                            const float* __restrict__ Wij, const float* __restrict__ WU,
                            const float* __restrict__ br, const float* __restrict__ bz,
                            const float* __restrict__ bij,
                            unsigned short* __restrict__ wp1, unsigned short* __restrict__ wp2,
                            float* __restrict__ bfused) {
  int blk = blockIdx.x, lane = threadIdx.x;
  if (blk < 832) {                       // 13 kb * 64 ntiles for W'
    int kb = blk >> 6, nt = blk & 63;
    int n = nt * 16 + (lane & 15);
    int kb8 = kb * 32 + (lane >> 4) * 8;
    unsigned short v[8];
#pragma unroll
    for (int j = 0; j < 8; ++j) {
      int k = kb8 + j; float w;
      if (n < 384) w = Wr[n * 416 + k];
      else if (n < 896) { int u = (n - 384) >> 2, g = (n - 384) & 3; w = Wz[(g * 128 + u) * 416 + k]; }
      else { int u = n - 896; w = (k >= 384) ? Wij[u * 32 + (k - 384)] : 0.f; }
      v[j] = f2bf(w);
    }
    ushort4v* dst = (ushort4v*)(wp1 + ((size_t)(kb * 64 + nt) * 64 + lane) * 8);
    dst[0] = (ushort4v){v[0], v[1], v[2], v[3]};
    dst[1] = (ushort4v){v[4], v[5], v[6], v[7]};
  } else if (blk < 832 + 96) {           // 12 kb * 8 ntiles for WU'
    int b2 = blk - 832;
    int kb = b2 >> 3, nt = b2 & 7;
    int n = nt * 16 + (lane & 15);
    int kb8 = kb * 32 + (lane >> 4) * 8;
    unsigned short v[8];
#pragma unroll
    for (int j = 0; j < 8; ++j) {
      int c = kb8 + j;
      int s = (c < 128) ? c + 128 : (c < 256 ? c - 128 : c);  // block swap
      v[j] = f2bf(WU[n * 384 + s]);
    }
    ushort4v* dst = (ushort4v*)(wp2 + ((size_t)(kb * 8 + nt) * 64 + lane) * 8);
    dst[0] = (ushort4v){v[0], v[1], v[2], v[3]};
    dst[1] = (ushort4v){v[4], v[5], v[6], v[7]};
  } else if (blk == 928) {               // fused bias (1024 fp32)
#pragma unroll
    for (int i = 0; i < 16; ++i) {
      int n = lane * 16 + i; float v;
      if (n < 384) v = br[n];
      else if (n < 896) { int u = (n - 384) >> 2, g = (n - 384) & 3; v = bz[g * 128 + u]; }
      else v = bij[n - 896];
      bfused[n] = v;
    }
  } else {                               // zero progress flags (LLC-visible)
    for (int i = lane; i < 160; i += 64)
      __hip_atomic_store(&g_progress[i], 0, __ATOMIC_RELAXED, __HIP_MEMORY_SCOPE_AGENT);
  }
}

// one GEMM1 K-step (16 MFMA over the wave's 64n x 64b tile)
#define G1_STEP(KB)                                                                        \
  {                                                                                        \
    bf16x8 wf[4], qf[4];                                                                   \
    _Pragma("unroll")                                                                      \
    for (int mt = 0; mt < 4; ++mt)                                                         \
      wf[mt] = *(const bf16x8*)(wp1 + ((size_t)((KB) * 64 + ntb + mt) * 64 + lane) * 8);   \
    _Pragma("unroll")                                                                      \
    for (int bt = 0; bt < 4; ++bt)                                                         \
      qf[bt] = *(const bf16x8*)(lds + (size_t)(bt * 16 + l15) * QPITCH + (KB) * 32 + quad * 8); \
    _Pragma("unroll")                                                                      \
    for (int mt = 0; mt < 4; ++mt)                                                         \
      _Pragma("unroll")                                                                    \
      for (int bt = 0; bt < 4; ++bt)                                                       \
        acc[mt][bt] = __builtin_amdgcn_mfma_f32_16x16x32_bf16(wf[mt], qf[bt], acc[mt][bt], 0, 0, 0); \
  }

// ---------------------------------------------------------------------------
// Persistent wavefront kernel. LDS layout (155,648 B):
//   q bf16 [64][QPITCH]              @ 0       (54,272 B)  cols: ht|hl|hd|x
//   htopF fp32 [64][HPITCH]          @ 54,272  (33,792 B)  own h(l-1)
//   hlD0/hlD1 fp32 [64][HPITCH]      @ 88,064 / 121,856    h_left double buf
// ---------------------------------------------------------------------------
__global__ __launch_bounds__(1024)
void gru_persist(const float* __restrict__ x, const float* __restrict__ bfused,
                 const unsigned short* __restrict__ wp1, const unsigned short* __restrict__ wp2,
                 float* __restrict__ ring, float* __restrict__ scratch,
                 float* __restrict__ out) {
  const int blk = blockIdx.x;
  const int rc = (blk < 80) ? blk : blk - 80;
  const int bh = (blk < 80) ? 0 : 1;
  const int tid = threadIdx.x;
  const int wave = tid >> 6, lane = tid & 63;
  const int quad = lane >> 4, l15 = lane & 15;

  extern __shared__ char smem[];
  unsigned short* lds = (unsigned short*)smem;
  float* htopF = (float*)(smem + 54272);
  float* hlD0  = (float*)(smem + 88064);
  float* hlD1  = (float*)(smem + 121856);

  float* scr  = scratch + (size_t)blk * 24576;  // per-block, own-L2 only
  float* hz_s = scr;
  float* zi_s = scr + 8192;
  float* cw_s = scr + 16384;
  float* ringMine = ring + (size_t)blk * 24576;  // 3 slots x 8192 fp32

  // ---- init: zero h buffers + q cols 0..383; stage x for l=0 ----
  for (int i = tid; i < 64 * HPITCH; i += 1024) { htopF[i] = 0.f; hlD0[i] = 0.f; hlD1[i] = 0.f; }
  {
    int r = tid >> 4, c0 = (tid & 15) * 24;      // 64 rows x 384 cols
#pragma unroll
    for (int j = 0; j < 6; ++j)
      *(ushort4v*)(lds + (size_t)r * QPITCH + c0 + j * 4) = (ushort4v){0, 0, 0, 0};
  }
  {
    const float* xb = x + rc;                    // inputs[b][c][0][rc]
    int i2 = tid * 2, bb = i2 >> 5, c = i2 & 31;
    float v0 = xb[(size_t)(bh * 2048 + i2) * 6400];
    float v1 = xb[(size_t)(bh * 2048 + i2 + 1) * 6400];
    *(ushort2v*)(lds + (size_t)bb * QPITCH + 384 + c) = (ushort2v){f2bf(v0), f2bf(v1)};
  }
  __syncthreads();

  const int ntb = wave * 4;
  const int m2 = wave >> 1, bsel = wave & 1;

  for (int l = 0; l < 80; ++l) {
    // ---- GEMM1 part A: kb {0..3, 8..12} (ht, hd, x) — no neighbor needed ----
    f32x4 acc[4][4];
#pragma unroll
    for (int mt = 0; mt < 4; ++mt)
#pragma unroll
      for (int bt = 0; bt < 4; ++bt) acc[mt][bt] = (f32x4){0.f, 0.f, 0.f, 0.f};
#pragma unroll
    for (int t = 0; t < 9; ++t) {
      const int kb = (t < 4) ? t : t + 4;
      G1_STEP(kb)
    }

    // ---- spin: left neighbor produced h(l, rc-1); right consumer freed slot ----
    if (wave == 0) {
      if (rc > 0)
        while (__hip_atomic_load(&g_progress[blk - 1], __ATOMIC_RELAXED, __HIP_MEMORY_SCOPE_AGENT) < l + 1)
          __builtin_amdgcn_s_sleep(1);
      if (rc < 79)
        while (__hip_atomic_load(&g_progress[blk + 1], __ATOMIC_RELAXED, __HIP_MEMORY_SCOPE_AGENT) < l - 2)
          __builtin_amdgcn_s_sleep(1);
    }
    asm volatile("" ::: "memory");
    __syncthreads();

    // ---- stage B: h_left from neighbor ring slot (LLC via sc1 loads) ----
    if (rc > 0) {
      float* src = ring + (size_t)(blk - 1) * 24576 + (size_t)(l % 3) * 8192;
      int idx = tid * 8, bl = idx >> 7, u = idx & 127;
      float v[8];
#pragma unroll
      for (int j = 0; j < 8; ++j)
        v[j] = __hip_atomic_load(&src[idx + j], __ATOMIC_RELAXED, __HIP_MEMORY_SCOPE_AGENT);
      float* hlF = (l & 1) ? hlD1 : hlD0;
      *(f32x4*)(hlF + bl * HPITCH + u)     = (f32x4){v[0], v[1], v[2], v[3]};
      *(f32x4*)(hlF + bl * HPITCH + u + 4) = (f32x4){v[4], v[5], v[6], v[7]};
      *(ushort4v*)(lds + (size_t)bl * QPITCH + 128 + u)     = (ushort4v){f2bf(v[0]), f2bf(v[1]), f2bf(v[2]), f2bf(v[3])};
      *(ushort4v*)(lds + (size_t)bl * QPITCH + 128 + u + 4) = (ushort4v){f2bf(v[4]), f2bf(v[5]), f2bf(v[6]), f2bf(v[7])};
    }
    // rc==0: hl columns stay zero forever (r-RMW writes r*0=0)
    __syncthreads();

    // ---- GEMM1 part B: kb 4..7 (hl) ----
#pragma unroll
    for (int kb = 4; kb < 8; ++kb) { G1_STEP(kb) }
    __syncthreads();   // all q reads done before in-place RMW

    // ---- elementwise ----
    if (wave < 6) {
      // r class: sigmoid, A2' = r*q in place (shift maps r col -> q col)
      const int rn0 = wave * 64;
      const int shift = (rn0 < 128) ? 128 : (rn0 < 256 ? -128 : 0);
#pragma unroll
      for (int mt = 0; mt < 4; ++mt)
#pragma unroll
        for (int bt = 0; bt < 4; ++bt) {
          int n0 = rn0 + mt * 16 + quad * 4;
          int row = bt * 16 + l15;
          unsigned short* p = lds + (size_t)row * QPITCH + n0 + shift;
          ushort4v qv = *(ushort4v*)p;
          ushort4v o;
#pragma unroll
          for (int g = 0; g < 4; ++g) {
            float r = sigm(acc[mt][bt][g] + bfused[n0 + g]);
            o[g] = f2bf(bf2f(qv[g]) * r);
          }
          *(ushort4v*)p = o;
        }
    } else if (wave < 14) {
      // z class: lane-local softmax over 4 gates; fold fp32 h's from LDS
      const float* hlF = (l & 1) ? hlD1 : hlD0;
      const float* hdF = (l & 1) ? hlD0 : hlD1;
#pragma unroll
      for (int mt = 0; mt < 4; ++mt)
#pragma unroll
        for (int bt = 0; bt < 4; ++bt) {
          int nb = wave * 64 + mt * 16 + quad * 4;
          int u = (nb - 384) >> 2;
          int bl = bt * 16 + l15;
          float v0 = acc[mt][bt][0] + bfused[nb];
          float v1 = acc[mt][bt][1] + bfused[nb + 1];
          float v2 = acc[mt][bt][2] + bfused[nb + 2];
          float v3 = acc[mt][bt][3] + bfused[nb + 3];
          float m = fmaxf(fmaxf(v0, v1), fmaxf(v2, v3));
          float e0 = __expf(v0 - m), e1 = __expf(v1 - m);
          float e2 = __expf(v2 - m), e3 = __expf(v3 - m);
          float inv = 1.f / (e0 + e1 + e2 + e3);
          float hl = hlF[bl * HPITCH + u];
          float ht = htopF[bl * HPITCH + u];
          float hd = hdF[bl * HPITCH + u];
          hz_s[bl * 128 + u] = (e1 * hl + e2 * ht + e3 * hd) * inv;  // zl,zt,zd
          zi_s[bl * 128 + u] = e0 * inv;
        }
    } else {
      // wij class: cw = acc + bij
#pragma unroll
      for (int mt = 0; mt < 4; ++mt)
#pragma unroll
        for (int bt = 0; bt < 4; ++bt) {
          int n0 = wave * 64 + mt * 16 + quad * 4;
          int uw = n0 - 896;
          int bl = bt * 16 + l15;
          f32x4 o;
#pragma unroll
          for (int g = 0; g < 4; ++g) o[g] = acc[mt][bt][g] + bfused[n0 + g];
          *(f32x4*)(cw_s + bl * 128 + uw) = o;
        }
    }
    __syncthreads();

    // ---- GEMM2: hU^T = WU' @ A2'^T (M=128 u, K=384, N=64 bl) ----
    f32x4 acc2[2];
    acc2[0] = (f32x4){0.f, 0.f, 0.f, 0.f};
    acc2[1] = (f32x4){0.f, 0.f, 0.f, 0.f};
    for (int kb = 0; kb < 12; ++kb) {
      bf16x8 wf = *(const bf16x8*)(wp2 + ((size_t)(kb * 8 + m2) * 64 + lane) * 8);
      bf16x8 q0 = *(const bf16x8*)(lds + (size_t)((bsel * 2 + 0) * 16 + l15) * QPITCH + kb * 32 + quad * 8);
      bf16x8 q1 = *(const bf16x8*)(lds + (size_t)((bsel * 2 + 1) * 16 + l15) * QPITCH + kb * 32 + quad * 8);
      acc2[0] = __builtin_amdgcn_mfma_f32_16x16x32_bf16(wf, q0, acc2[0], 0, 0, 0);
      acc2[1] = __builtin_amdgcn_mfma_f32_16x16x32_bf16(wf, q1, acc2[1], 0, 0, 0);
    }
    __syncthreads();   // GEMM2 q reads done before combine overwrites q ht cols

    // ---- combine: h = hz + zi*tanh(cw + hU); publish + keep local copies ----
#pragma unroll
    for (int bt = 0; bt < 2; ++bt) {
      int bl = (bsel * 2 + bt) * 16 + l15;
      int u0 = m2 * 16 + quad * 4;
      f32x4 cw = *(f32x4*)(cw_s + bl * 128 + u0);
      f32x4 hz = *(f32x4*)(hz_s + bl * 128 + u0);
      f32x4 zi = *(f32x4*)(zi_s + bl * 128 + u0);
      f32x4 h;
#pragma unroll
      for (int g = 0; g < 4; ++g)
        h[g] = hz[g] + zi[g] * tanh_fast(cw[g] + acc2[bt][g]);
      float* dst = ringMine + (size_t)(l % 3) * 8192 + bl * 128 + u0;
#pragma unroll
      for (int g = 0; g < 4; ++g)   // sc1 stores -> LLC, neighbor-visible
        __hip_atomic_store(&dst[g], h[g], __ATOMIC_RELAXED, __HIP_MEMORY_SCOPE_AGENT);
      *(f32x4*)(htopF + bl * HPITCH + u0) = h;                    // next ht fp32
      *(ushort4v*)(lds + (size_t)bl * QPITCH + u0) =              // next ht bf16
          (ushort4v){f2bf(h[0]), f2bf(h[1]), f2bf(h[2]), f2bf(h[3])};
      if (rc == 79 && l == 79)
        *(f32x4*)(out + (size_t)(bh * 64 + bl) * 128 + u0) = h;
    }
    // ---- stage A for l+1 (hd <- this step's hl fp32; x scatter) ----
    if (l < 79) {
      const int L = l + 1;
      const float* hdF = (L & 1) ? hlD0 : hlD1;
      int idx = tid * 8, bl = idx >> 7, u = idx & 127;
      f32x4 a = *(const f32x4*)(hdF + bl * HPITCH + u);
      f32x4 b = *(const f32x4*)(hdF + bl * HPITCH + u + 4);
      *(ushort4v*)(lds + (size_t)bl * QPITCH + 256 + u)     = (ushort4v){f2bf(a[0]), f2bf(a[1]), f2bf(a[2]), f2bf(a[3])};
      *(ushort4v*)(lds + (size_t)bl * QPITCH + 256 + u + 4) = (ushort4v){f2bf(b[0]), f2bf(b[1]), f2bf(b[2]), f2bf(b[3])};
      const float* xb = x + (size_t)L * 80 + rc;
      int i2 = tid * 2, bb = i2 >> 5, c = i2 & 31;
      float v0 = xb[(size_t)(bh * 2048 + i2) * 6400];
      float v1 = xb[(size_t)(bh * 2048 + i2 + 1) * 6400];
      *(ushort2v*)(lds + (size_t)bb * QPITCH + 384 + c) = (ushort2v){f2bf(v0), f2bf(v1)};
    }
    __syncthreads();   // drains every wave's ring stores (waitcnt before barrier)
    if (tid == 0)
      __hip_atomic_store(&g_progress[blk], l + 1, __ATOMIC_RELAXED, __HIP_MEMORY_SCOPE_AGENT);
  }
}

// ---------------------------------------------------------------------------
extern "C" void kernel_launch(void* const* d_in, const int* in_sizes, int n_in,
                              void* d_out, int out_size, void* d_ws, size_t ws_size,
                              hipStream_t stream) {
  const float* x   = (const float*)d_in[0];
  const float* Wr  = (const float*)d_in[1];
  const float* br  = (const float*)d_in[2];
  const float* Wz  = (const float*)d_in[3];
  const float* bz  = (const float*)d_in[4];
  const float* Wij = (const float*)d_in[5];
  const float* bij = (const float*)d_in[6];
  const float* WU  = (const float*)d_in[7];
  float* out = (float*)d_out;

  // ws layout (~32.4 MB, unchanged footprint)
  char* ws = (char*)d_ws;
  unsigned short* wp1 = (unsigned short*)(ws);                 // 851,968 B
  unsigned short* wp2 = (unsigned short*)(ws + 851968);        //  98,304 B
  float* bfused       = (float*)(ws + 950272);                 //   4,096 B
  float* ring         = (float*)(ws + 954368);                 // 15,728,640 B (160 blk x 3 slots x 8192 f32)
  float* scratch      = (float*)(ws + 954368 + 15728640);      // 15,728,640 B (160 blk x 24576 f32)

  (void)hipFuncSetAttribute((const void*)gru_persist,
                            hipFuncAttributeMaxDynamicSharedMemorySize, 155648);

  prep_kernel<<<930, 64, 0, stream>>>(Wr, Wz, Wij, WU, br, bz, bij, wp1, wp2, bfused);
  gru_persist<<<160, 1024, 155648, stream>>>(x, bfused, wp1, wp2, ring, scratch, out);
}

// Round 2
// 8354.294 us; speedup vs baseline: 1.3960x; 1.3960x over previous
//
#include <hip/hip_runtime.h>
#include <stdint.h>

// SpatialGRU on MI355X, round 4: persistent kernel, latency-amplifier fixes.
// Round-3 post-mortem: T_slot=73us, FETCH=755KB/block-step == weight stream
// re-fetched from LLC every step (L2 thrashed by x-line overfetch 256KB/step
// + scratch). Fixes: (1) nt x loads (no L2 alloc) + reg prefetch one step
// ahead; (2) GEMM2 weights + bias hoisted to registers for the whole l-loop,
// part-B weights (kb4,5) prefetched before the spin; (3) ring handoff via
// dwordx4 sc0 sc1 (LLC-coherent vector ops) instead of scalar atomics;
// (4) single-lane flag polling. Protocol itself unchanged (proven correct).

typedef __bf16 bf16x8 __attribute__((ext_vector_type(8)));
typedef float  f32x4  __attribute__((ext_vector_type(4)));
typedef unsigned short ushort4v __attribute__((ext_vector_type(4)));
typedef unsigned short ushort2v __attribute__((ext_vector_type(2)));

#define QPITCH 424   // 416 q cols + 8 pad (bf16 elems)
#define HPITCH 132   // fp32 h rows padded +4

__device__ int g_progress[160];   // cells completed per block

__device__ __forceinline__ unsigned short f2bf(float x) {
  unsigned int u = __builtin_bit_cast(unsigned int, x);
  u = u + 0x7FFFu + ((u >> 16) & 1u);          // round-to-nearest-even
  return (unsigned short)(u >> 16);
}
__device__ __forceinline__ float bf2f(unsigned short h) {
  unsigned int u = ((unsigned int)h) << 16;
  return __builtin_bit_cast(float, u);
}
__device__ __forceinline__ float sigm(float x) {
  x = fminf(fmaxf(x, -30.f), 30.f);
  return 1.f / (1.f + __expf(-x));
}
__device__ __forceinline__ float tanh_fast(float x) {
  x = fminf(fmaxf(x, -15.f), 15.f);
  float e = __expf(2.f * x);
  return (e - 1.f) / (e + 1.f);
}

// LLC-coherent (L2-bypass) 32B load/store for the cross-XCD ring.
__device__ __forceinline__ void llc_load32(const float* p, f32x4& a, f32x4& b) {
  asm volatile("global_load_dwordx4 %0, %2, off sc0 sc1\n\t"
               "global_load_dwordx4 %1, %3, off sc0 sc1\n\t"
               "s_waitcnt vmcnt(0)"
               : "=&v"(a), "=&v"(b)
               : "v"(p), "v"(p + 4)
               : "memory");
}
__device__ __forceinline__ void llc_store16(float* p, f32x4 v) {
  asm volatile("global_store_dwordx4 %0, %1, off sc0 sc1"
               :: "v"(p), "v"(v) : "memory");
}

// ---------------------------------------------------------------------------
// prep: pack fused W' (1024 x 416) and WU' (128 x 384) into MFMA A-fragment
// order (unchanged) + zero the progress flags.
// ---------------------------------------------------------------------------
__global__ void prep_kernel(const float* __restrict__ Wr, const float* __restrict__ Wz,
                            const float* __restrict__ Wij, const float* __restrict__ WU,
                            const float* __restrict__ br, const float* __restrict__ bz,
                            const float* __restrict__ bij,
                            unsigned short* __restrict__ wp1, unsigned short* __restrict__ wp2,
                            float* __restrict__ bfused) {
  int blk = blockIdx.x, lane = threadIdx.x;
  if (blk < 832) {                       // 13 kb * 64 ntiles for W'
    int kb = blk >> 6, nt = blk & 63;
    int n = nt * 16 + (lane & 15);
    int kb8 = kb * 32 + (lane >> 4) * 8;
    unsigned short v[8];
#pragma unroll
    for (int j = 0; j < 8; ++j) {
      int k = kb8 + j; float w;
      if (n < 384) w = Wr[n * 416 + k];
      else if (n < 896) { int u = (n - 384) >> 2, g = (n - 384) & 3; w = Wz[(g * 128 + u) * 416 + k]; }
      else { int u = n - 896; w = (k >= 384) ? Wij[u * 32 + (k - 384)] : 0.f; }
      v[j] = f2bf(w);
    }
    ushort4v* dst = (ushort4v*)(wp1 + ((size_t)(kb * 64 + nt) * 64 + lane) * 8);
    dst[0] = (ushort4v){v[0], v[1], v[2], v[3]};
    dst[1] = (ushort4v){v[4], v[5], v[6], v[7]};
  } else if (blk < 832 + 96) {           // 12 kb * 8 ntiles for WU'
    int b2 = blk - 832;
    int kb = b2 >> 3, nt = b2 & 7;
    int n = nt * 16 + (lane & 15);
    int kb8 = kb * 32 + (lane >> 4) * 8;
    unsigned short v[8];
#pragma unroll
    for (int j = 0; j < 8; ++j) {
      int c = kb8 + j;
      int s = (c < 128) ? c + 128 : (c < 256 ? c - 128 : c);  // block swap
      v[j] = f2bf(WU[n * 384 + s]);
    }
    ushort4v* dst = (ushort4v*)(wp2 + ((size_t)(kb * 8 + nt) * 64 + lane) * 8);
    dst[0] = (ushort4v){v[0], v[1], v[2], v[3]};
    dst[1] = (ushort4v){v[4], v[5], v[6], v[7]};
  } else if (blk == 928) {               // fused bias (1024 fp32)
#pragma unroll
    for (int i = 0; i < 16; ++i) {
      int n = lane * 16 + i; float v;
      if (n < 384) v = br[n];
      else if (n < 896) { int u = (n - 384) >> 2, g = (n - 384) & 3; v = bz[g * 128 + u]; }
      else v = bij[n - 896];
      bfused[n] = v;
    }
  } else {                               // zero progress flags
    for (int i = lane; i < 160; i += 64)
      __hip_atomic_store(&g_progress[i], 0, __ATOMIC_RELAXED, __HIP_MEMORY_SCOPE_AGENT);
  }
}

// one GEMM1 K-step, weights loaded inline
#define G1_STEP(KB)                                                                        \
  {                                                                                        \
    bf16x8 wf[4], qf[4];                                                                   \
    _Pragma("unroll")                                                                      \
    for (int mt = 0; mt < 4; ++mt)                                                         \
      wf[mt] = *(const bf16x8*)(wp1 + ((size_t)((KB) * 64 + ntb + mt) * 64 + lane) * 8);   \
    _Pragma("unroll")                                                                      \
    for (int bt = 0; bt < 4; ++bt)                                                         \
      qf[bt] = *(const bf16x8*)(lds + (size_t)(bt * 16 + l15) * QPITCH + (KB) * 32 + quad * 8); \
    _Pragma("unroll")                                                                      \
    for (int mt = 0; mt < 4; ++mt)                                                         \
      _Pragma("unroll")                                                                    \
      for (int bt = 0; bt < 4; ++bt)                                                       \
        acc[mt][bt] = __builtin_amdgcn_mfma_f32_16x16x32_bf16(wf[mt], qf[bt], acc[mt][bt], 0, 0, 0); \
  }

// one GEMM1 K-step with pre-loaded weights
#define G1_STEP_W(KB, WF)                                                                  \
  {                                                                                        \
    bf16x8 qf[4];                                                                          \
    _Pragma("unroll")                                                                      \
    for (int bt = 0; bt < 4; ++bt)                                                         \
      qf[bt] = *(const bf16x8*)(lds + (size_t)(bt * 16 + l15) * QPITCH + (KB) * 32 + quad * 8); \
    _Pragma("unroll")                                                                      \
    for (int mt = 0; mt < 4; ++mt)                                                         \
      _Pragma("unroll")                                                                    \
      for (int bt = 0; bt < 4; ++bt)                                                       \
        acc[mt][bt] = __builtin_amdgcn_mfma_f32_16x16x32_bf16((WF)[mt], qf[bt], acc[mt][bt], 0, 0, 0); \
  }

// ---------------------------------------------------------------------------
// Persistent wavefront kernel. LDS layout (155,648 B):
//   q bf16 [64][QPITCH]              @ 0       (54,272 B)  cols: ht|hl|hd|x
//   htopF fp32 [64][HPITCH]          @ 54,272  (33,792 B)  own h(l-1)
//   hlD0/hlD1 fp32 [64][HPITCH]      @ 88,064 / 121,856    h_left double buf
// ---------------------------------------------------------------------------
__global__ __launch_bounds__(1024)
void gru_persist(const float* __restrict__ x, const float* __restrict__ bfused,
                 const unsigned short* __restrict__ wp1, const unsigned short* __restrict__ wp2,
                 float* __restrict__ ring, float* __restrict__ scratch,
                 float* __restrict__ out) {
  const int blk = blockIdx.x;
  const int rc = (blk < 80) ? blk : blk - 80;
  const int bh = (blk < 80) ? 0 : 1;
  const int tid = threadIdx.x;
  const int wave = tid >> 6, lane = tid & 63;
  const int quad = lane >> 4, l15 = lane & 15;

  extern __shared__ char smem[];
  unsigned short* lds = (unsigned short*)smem;
  float* htopF = (float*)(smem + 54272);
  float* hlD0  = (float*)(smem + 88064);
  float* hlD1  = (float*)(smem + 121856);

  float* scr  = scratch + (size_t)blk * 24576;  // per-block, own-XCD L2
  float* hz_s = scr;
  float* zi_s = scr + 8192;
  float* cw_s = scr + 16384;
  float* ringMine = ring + (size_t)blk * 24576;  // 3 slots x 8192 fp32

  // ---- init: zero h buffers + q cols 0..383; stage x for l=0 ----
  for (int i = tid; i < 64 * HPITCH; i += 1024) { htopF[i] = 0.f; hlD0[i] = 0.f; hlD1[i] = 0.f; }
  {
    int r = tid >> 4, c0 = (tid & 15) * 24;      // 64 rows x 384 cols
#pragma unroll
    for (int j = 0; j < 6; ++j)
      *(ushort4v*)(lds + (size_t)r * QPITCH + c0 + j * 4) = (ushort4v){0, 0, 0, 0};
  }
  {
    const float* xb = x + rc;                    // inputs[b][c][0][rc]
    int i2 = tid * 2;
    float v0 = __builtin_nontemporal_load(xb + (size_t)(bh * 2048 + i2) * 6400);
    float v1 = __builtin_nontemporal_load(xb + (size_t)(bh * 2048 + i2 + 1) * 6400);
    int bb = i2 >> 5, c = i2 & 31;
    *(ushort2v*)(lds + (size_t)bb * QPITCH + 384 + c) = (ushort2v){f2bf(v0), f2bf(v1)};
  }
  __syncthreads();

  const int ntb = wave * 4;
  const int m2 = wave >> 1, bsel = wave & 1;

  // ---- hoisted loop invariants: GEMM2 weights (48 VGPR) + bias (16) ----
  bf16x8 wf2[12];
#pragma unroll
  for (int kb = 0; kb < 12; ++kb)
    wf2[kb] = *(const bf16x8*)(wp2 + ((size_t)(kb * 8 + m2) * 64 + lane) * 8);
  f32x4 biasv[4];
#pragma unroll
  for (int mt = 0; mt < 4; ++mt)
    biasv[mt] = *(const f32x4*)(bfused + wave * 64 + mt * 16 + quad * 4);

  for (int l = 0; l < 80; ++l) {
    // ---- x prefetch for l+1 (nt: no L2 pollution; latency hidden to B1) ----
    float xn0 = 0.f, xn1 = 0.f;
    const int i2 = tid * 2;
    if (l < 79) {
      const float* xb = x + (size_t)(l + 1) * 80 + rc;
      xn0 = __builtin_nontemporal_load(xb + (size_t)(bh * 2048 + i2) * 6400);
      xn1 = __builtin_nontemporal_load(xb + (size_t)(bh * 2048 + i2 + 1) * 6400);
    }

    // ---- GEMM1 part A: kb {0..3, 8..12} (ht, hd, x) — neighbor-free ----
    f32x4 acc[4][4];
#pragma unroll
    for (int mt = 0; mt < 4; ++mt)
#pragma unroll
      for (int bt = 0; bt < 4; ++bt) acc[mt][bt] = (f32x4){0.f, 0.f, 0.f, 0.f};
#pragma unroll
    for (int t = 0; t < 9; ++t) {
      const int kb = (t < 4) ? t : t + 4;
      G1_STEP(kb)
    }

    // ---- prefetch part-B weights kb 4,5 (complete during spin/barrier) ----
    bf16x8 wfB[2][4];
#pragma unroll
    for (int kb = 0; kb < 2; ++kb)
#pragma unroll
      for (int mt = 0; mt < 4; ++mt)
        wfB[kb][mt] = *(const bf16x8*)(wp1 + ((size_t)((kb + 4) * 64 + ntb + mt) * 64 + lane) * 8);

    // ---- spin (single lane): left done row l; right consumed slot ----
    if (tid == 0) {
      if (rc > 0)
        while (__hip_atomic_load(&g_progress[blk - 1], __ATOMIC_RELAXED, __HIP_MEMORY_SCOPE_AGENT) < l + 1)
          __builtin_amdgcn_s_sleep(1);
      if (rc < 79)
        while (__hip_atomic_load(&g_progress[blk + 1], __ATOMIC_RELAXED, __HIP_MEMORY_SCOPE_AGENT) < l - 2)
          __builtin_amdgcn_s_sleep(1);
    }
    asm volatile("" ::: "memory");
    __syncthreads();                                             // B1

    // ---- stage B: h_left from neighbor ring (LLC dwordx4) ----
    if (rc > 0) {
      const float* src = ring + (size_t)(blk - 1) * 24576 + (size_t)(l % 3) * 8192 + tid * 8;
      f32x4 a, b;
      llc_load32(src, a, b);
      int bl = (tid * 8) >> 7, u = (tid * 8) & 127;
      float* hlF = (l & 1) ? hlD1 : hlD0;
      *(f32x4*)(hlF + bl * HPITCH + u)     = a;
      *(f32x4*)(hlF + bl * HPITCH + u + 4) = b;
      *(ushort4v*)(lds + (size_t)bl * QPITCH + 128 + u)     = (ushort4v){f2bf(a[0]), f2bf(a[1]), f2bf(a[2]), f2bf(a[3])};
      *(ushort4v*)(lds + (size_t)bl * QPITCH + 128 + u + 4) = (ushort4v){f2bf(b[0]), f2bf(b[1]), f2bf(b[2]), f2bf(b[3])};
    }
    // rc==0: hl columns stay zero forever
    __syncthreads();                                             // B2

    // ---- GEMM1 part B: kb 4..7 (hl) ----
    G1_STEP_W(4, wfB[0])
    G1_STEP_W(5, wfB[1])
    G1_STEP(6)
    G1_STEP(7)
    __syncthreads();                                             // B3

    // ---- elementwise ----
    if (wave < 6) {
      // r class: sigmoid, A2' = r*q in place (shift maps r col -> q col)
      const int rn0 = wave * 64;
      const int shift = (rn0 < 128) ? 128 : (rn0 < 256 ? -128 : 0);
#pragma unroll
      for (int mt = 0; mt < 4; ++mt)
#pragma unroll
        for (int bt = 0; bt < 4; ++bt) {
          int n0 = rn0 + mt * 16 + quad * 4;
          int row = bt * 16 + l15;
          unsigned short* p = lds + (size_t)row * QPITCH + n0 + shift;
          ushort4v qv = *(ushort4v*)p;
          ushort4v o;
#pragma unroll
          for (int g = 0; g < 4; ++g) {
            float r = sigm(acc[mt][bt][g] + biasv[mt][g]);
            o[g] = f2bf(bf2f(qv[g]) * r);
          }
          *(ushort4v*)p = o;
        }
    } else if (wave < 14) {
      // z class: lane-local softmax over 4 gates; fold fp32 h's from LDS
      const float* hlF = (l & 1) ? hlD1 : hlD0;
      const float* hdF = (l & 1) ? hlD0 : hlD1;
#pragma unroll
      for (int mt = 0; mt < 4; ++mt)
#pragma unroll
        for (int bt = 0; bt < 4; ++bt) {
          int nb = wave * 64 + mt * 16 + quad * 4;
          int u = (nb - 384) >> 2;
          int bl = bt * 16 + l15;
          float v0 = acc[mt][bt][0] + biasv[mt][0];
          float v1 = acc[mt][bt][1] + biasv[mt][1];
          float v2 = acc[mt][bt][2] + biasv[mt][2];
          float v3 = acc[mt][bt][3] + biasv[mt][3];
          float m = fmaxf(fmaxf(v0, v1), fmaxf(v2, v3));
          float e0 = __expf(v0 - m), e1 = __expf(v1 - m);
          float e2 = __expf(v2 - m), e3 = __expf(v3 - m);
          float inv = 1.f / (e0 + e1 + e2 + e3);
          float hl = hlF[bl * HPITCH + u];
          float ht = htopF[bl * HPITCH + u];
          float hd = hdF[bl * HPITCH + u];
          hz_s[bl * 128 + u] = (e1 * hl + e2 * ht + e3 * hd) * inv;  // zl,zt,zd
          zi_s[bl * 128 + u] = e0 * inv;
        }
    } else {
      // wij class: cw = acc + bij
#pragma unroll
      for (int mt = 0; mt < 4; ++mt)
#pragma unroll
        for (int bt = 0; bt < 4; ++bt) {
          int n0 = wave * 64 + mt * 16 + quad * 4;
          int uw = n0 - 896;
          int bl = bt * 16 + l15;
          f32x4 o;
#pragma unroll
          for (int g = 0; g < 4; ++g) o[g] = acc[mt][bt][g] + biasv[mt][g];
          *(f32x4*)(cw_s + bl * 128 + uw) = o;
        }
    }
    __syncthreads();                                             // B4

    // ---- GEMM2: hU^T = WU' @ A2'^T (weights in registers) ----
    f32x4 acc2[2];
    acc2[0] = (f32x4){0.f, 0.f, 0.f, 0.f};
    acc2[1] = (f32x4){0.f, 0.f, 0.f, 0.f};
#pragma unroll
    for (int kb = 0; kb < 12; ++kb) {
      bf16x8 q0 = *(const bf16x8*)(lds + (size_t)((bsel * 2 + 0) * 16 + l15) * QPITCH + kb * 32 + quad * 8);
      bf16x8 q1 = *(const bf16x8*)(lds + (size_t)((bsel * 2 + 1) * 16 + l15) * QPITCH + kb * 32 + quad * 8);
      acc2[0] = __builtin_amdgcn_mfma_f32_16x16x32_bf16(wf2[kb], q0, acc2[0], 0, 0, 0);
      acc2[1] = __builtin_amdgcn_mfma_f32_16x16x32_bf16(wf2[kb], q1, acc2[1], 0, 0, 0);
    }
    __syncthreads();                                             // B5

    // ---- combine: h = hz + zi*tanh(cw + hU); publish + local copies ----
#pragma unroll
    for (int bt = 0; bt < 2; ++bt) {
      int bl = (bsel * 2 + bt) * 16 + l15;
      int u0 = m2 * 16 + quad * 4;
      f32x4 cw = *(f32x4*)(cw_s + bl * 128 + u0);
      f32x4 hz = *(f32x4*)(hz_s + bl * 128 + u0);
      f32x4 zi = *(f32x4*)(zi_s + bl * 128 + u0);
      f32x4 h;
#pragma unroll
      for (int g = 0; g < 4; ++g)
        h[g] = hz[g] + zi[g] * tanh_fast(cw[g] + acc2[bt][g]);
      llc_store16(ringMine + (size_t)(l % 3) * 8192 + bl * 128 + u0, h);
      *(f32x4*)(htopF + bl * HPITCH + u0) = h;                    // next ht fp32
      *(ushort4v*)(lds + (size_t)bl * QPITCH + u0) =              // next ht bf16
          (ushort4v){f2bf(h[0]), f2bf(h[1]), f2bf(h[2]), f2bf(h[3])};
      if (rc == 79 && l == 79)
        *(f32x4*)(out + (size_t)(bh * 64 + bl) * 128 + u0) = h;
    }
    // ---- stage A for l+1 (hd <- this step's hl fp32; x from prefetch) ----
    if (l < 79) {
      const float* hdF = ((l + 1) & 1) ? hlD0 : hlD1;
      int idx = tid * 8, bl = idx >> 7, u = idx & 127;
      f32x4 a = *(const f32x4*)(hdF + bl * HPITCH + u);
      f32x4 b = *(const f32x4*)(hdF + bl * HPITCH + u + 4);
      *(ushort4v*)(lds + (size_t)bl * QPITCH + 256 + u)     = (ushort4v){f2bf(a[0]), f2bf(a[1]), f2bf(a[2]), f2bf(a[3])};
      *(ushort4v*)(lds + (size_t)bl * QPITCH + 256 + u + 4) = (ushort4v){f2bf(b[0]), f2bf(b[1]), f2bf(b[2]), f2bf(b[3])};
      int bb = i2 >> 5, c = i2 & 31;
      *(ushort2v*)(lds + (size_t)bb * QPITCH + 384 + c) = (ushort2v){f2bf(xn0), f2bf(xn1)};
    }
    __syncthreads();                                             // B6 (drains ring stores)
    if (tid == 0)
      __hip_atomic_store(&g_progress[blk], l + 1, __ATOMIC_RELAXED, __HIP_MEMORY_SCOPE_AGENT);
  }
}

// ---------------------------------------------------------------------------
extern "C" void kernel_launch(void* const* d_in, const int* in_sizes, int n_in,
                              void* d_out, int out_size, void* d_ws, size_t ws_size,
                              hipStream_t stream) {
  const float* x   = (const float*)d_in[0];
  const float* Wr  = (const float*)d_in[1];
  const float* br  = (const float*)d_in[2];
  const float* Wz  = (const float*)d_in[3];
  const float* bz  = (const float*)d_in[4];
  const float* Wij = (const float*)d_in[5];
  const float* bij = (const float*)d_in[6];
  const float* WU  = (const float*)d_in[7];
  float* out = (float*)d_out;

  // ws layout (~32.4 MB, unchanged footprint)
  char* ws = (char*)d_ws;
  unsigned short* wp1 = (unsigned short*)(ws);                 // 851,968 B
  unsigned short* wp2 = (unsigned short*)(ws + 851968);        //  98,304 B
  float* bfused       = (float*)(ws + 950272);                 //   4,096 B
  float* ring         = (float*)(ws + 954368);                 // 15,728,640 B (160 blk x 3 slots x 8192 f32)
  float* scratch      = (float*)(ws + 954368 + 15728640);      // 15,728,640 B (160 blk x 24576 f32)

  (void)hipFuncSetAttribute((const void*)gru_persist,
                            hipFuncAttributeMaxDynamicSharedMemorySize, 155648);

  prep_kernel<<<930, 64, 0, stream>>>(Wr, Wz, Wij, WU, br, bz, bij, wp1, wp2, bfused);
  gru_persist<<<160, 1024, 155648, stream>>>(x, bfused, wp1, wp2, ring, scratch, out);
}